// Round 5
// baseline (1329.210 us; speedup 1.0000x reference)
//
#include <hip/hip_runtime.h>
#include <hip/hip_bf16.h>
#include <cmath>

#define NN 49920
#define EE 200000
#define BB 128

typedef __attribute__((ext_vector_type(8))) short short8;
typedef __attribute__((ext_vector_type(4))) float floatx4;

__device__ __forceinline__ float bits2f(unsigned short u) {
    union { unsigned int i; float f; } c; c.i = ((unsigned int)u) << 16; return c.f;
}
__device__ __forceinline__ unsigned short f2bits(float f) {
    union { float f; unsigned int i; } c; c.f = f;
    unsigned int x = c.i;
    return (unsigned short)((x + 0x7fffu + ((x >> 16) & 1u)) >> 16);   // RNE, finite inputs
}

// ---------------- small utility kernels ----------------
__global__ void zero_int_kernel(int* __restrict__ p, int n) {
    int i = blockIdx.x * blockDim.x + threadIdx.x;
    if (i < n) p[i] = 0;
}

__global__ void convert_bf16_kernel(const float* __restrict__ src, unsigned short* __restrict__ dst, int n) {
    int i = blockIdx.x * blockDim.x + threadIdx.x;
    if (i < n) dst[i] = f2bits(src[i]);
}

// ---------------- bf16 MFMA GEMM: C(bf16) = A@W + bias ----------------
// A [M,K] bf16 row-major, W [K,N] bf16 row-major, bias [N] f32, C [M,N] bf16.
// Block: 256 thr = 4 waves, 128x128 C-tile (waves 2x2 of 64x64), BK=32.
#define LDK 40   // padded LDS k-stride in ushorts (80B: keeps b128 16B-aligned, 2-way banks)

__global__ __launch_bounds__(256) void mfma_gemm_kernel(
    const unsigned short* __restrict__ A, const unsigned short* __restrict__ W,
    const float* __restrict__ bias, unsigned short* __restrict__ C,
    int M, int K, int N) {
    __shared__ unsigned short As[128 * LDK];
    __shared__ unsigned short Bt[128 * LDK];   // B transposed: Bt[n][k]
    int tid = threadIdx.x;
    int lane = tid & 63, wid = tid >> 6;
    int gm0 = blockIdx.y * 128, gn0 = blockIdx.x * 128;
    int wm = (wid & 1) * 64, wn = (wid >> 1) * 64;
    int row15 = lane & 15, quad = lane >> 4;

    floatx4 acc[4][4];
#pragma unroll
    for (int i = 0; i < 4; i++)
#pragma unroll
        for (int j = 0; j < 4; j++)
#pragma unroll
            for (int r = 0; r < 4; r++) acc[i][j][r] = 0.f;

    for (int k0 = 0; k0 < K; k0 += 32) {
        __syncthreads();
        // stage A: 128 rows x 32 k (bf16), k-contiguous
        {
            int idx = tid;
#pragma unroll
            for (int l = 0; l < 2; l++, idx += 256) {
                int r = idx >> 2;           // 0..127
                int kp = (idx & 3) * 8;     // 0,8,16,24
                *(uint4*)&As[r * LDK + kp] = *(const uint4*)&A[(size_t)(gm0 + r) * K + k0 + kp];
            }
        }
        // stage B with transpose: W[k][n] -> Bt[n][k]
        {
            int idx = tid;
#pragma unroll
            for (int l = 0; l < 2; l++, idx += 256) {
                int kr = idx >> 4;           // 0..31
                int cg = (idx & 15) * 8;     // 0..120
                union { uint4 v; unsigned short u[8]; } w;
                w.v = *(const uint4*)&W[(size_t)(k0 + kr) * N + gn0 + cg];
#pragma unroll
                for (int j = 0; j < 8; j++) Bt[(cg + j) * LDK + kr] = w.u[j];
            }
        }
        __syncthreads();
        short8 af[4], bfr[4];
#pragma unroll
        for (int i = 0; i < 4; i++)
            af[i] = *(const short8*)&As[(wm + 16 * i + row15) * LDK + quad * 8];
#pragma unroll
        for (int j = 0; j < 4; j++)
            bfr[j] = *(const short8*)&Bt[(wn + 16 * j + row15) * LDK + quad * 8];
#pragma unroll
        for (int i = 0; i < 4; i++)
#pragma unroll
            for (int j = 0; j < 4; j++)
                acc[i][j] = __builtin_amdgcn_mfma_f32_16x16x32_bf16(af[i], bfr[j], acc[i][j], 0, 0, 0);
    }

    // epilogue: C[row][col], row=(quad*4+r)+16i+wm, col=row15+16j+wn
    int colb = gn0 + wn + row15;
#pragma unroll
    for (int i = 0; i < 4; i++) {
#pragma unroll
        for (int j = 0; j < 4; j++) {
            int col = colb + 16 * j;
            float bv = bias[col];
#pragma unroll
            for (int r = 0; r < 4; r++) {
                int rrow = gm0 + wm + 16 * i + quad * 4 + r;
                C[(size_t)rrow * N + col] = f2bits(acc[i][j][r] + bv);
            }
        }
    }
}

// ---------------- edge scoring via MFMA ----------------
// 64 edges/block (E = 64*3125 exactly). 4 waves; wave w owns cols [ct*64+w*16, +16)
// per channel-iteration ct. ef tile = eattr(16x16, K zero-padded to 32) @ We(16x16)
// via one mfma per (tile,ct). C-layout: edge = 16t + quad*4 + r, col = lane&15.
template<int HC>
__global__ __launch_bounds__(256) void edge_score_mfma_kernel(
    const unsigned short* __restrict__ xl, const unsigned short* __restrict__ xr,
    const float* __restrict__ eattr, const float* __restrict__ We,
    const float* __restrict__ att, const int* __restrict__ ei,
    float* __restrict__ logits, int E) {
    constexpr int NIT = HC / 64;              // channel iterations
    constexpr int FE = (HC == 1024) ? 4 : 1;  // flush every FE iterations (head boundary)
    __shared__ int src_s[64], dst_s[64];
    __shared__ float logit_s[64 * 4];

    int tid = threadIdx.x;
    int e0 = blockIdx.x * 64;
    int lane = tid & 63, w = tid >> 6;
    int l15 = lane & 15, quad = lane >> 4;

    if (tid < 64) { src_s[tid] = ei[e0 + tid]; dst_s[tid] = ei[E + e0 + tid]; }
    logit_s[tid] = 0.f;
    __syncthreads();

    // A-frags (eattr, bf16, K padded 16->32): lane holds eattr[e0+16t+l15][quad*8+j]
    short8 afr[4];
#pragma unroll
    for (int t = 0; t < 4; t++) {
        union { short8 v; unsigned short u[8]; } a;
        if (quad < 2) {
            const float* ap = &eattr[(size_t)(e0 + 16 * t + l15) * 16 + quad * 8];
            float4 a0 = *(const float4*)ap;
            float4 a1 = *(const float4*)(ap + 4);
            a.u[0] = f2bits(a0.x); a.u[1] = f2bits(a0.y); a.u[2] = f2bits(a0.z); a.u[3] = f2bits(a0.w);
            a.u[4] = f2bits(a1.x); a.u[5] = f2bits(a1.y); a.u[6] = f2bits(a1.z); a.u[7] = f2bits(a1.w);
        } else {
#pragma unroll
            for (int j = 0; j < 8; j++) a.u[j] = 0;
        }
        afr[t] = a.v;
    }

    // per-lane xl/xr byte addresses for its 16 edges (col base = w*16 + l15)
    unsigned xla[16], xra[16];
#pragma unroll
    for (int t = 0; t < 4; t++)
#pragma unroll
        for (int r = 0; r < 4; r++) {
            int le = 16 * t + quad * 4 + r;
            xla[t * 4 + r] = ((unsigned)src_s[le] * HC + w * 16 + l15) * 2u;
            xra[t * 4 + r] = ((unsigned)dst_s[le] * HC + w * 16 + l15) * 2u;
        }

    float facc[16];
#pragma unroll
    for (int i = 0; i < 16; i++) facc[i] = 0.f;

    for (int ct = 0; ct < NIT; ct++) {
        int col = ct * 64 + w * 16 + l15;     // global channel for this lane
        // B-frag: lane holds We[quad*8+j][col], zero for k>=16
        union { short8 v; unsigned short u[8]; } b;
        if (quad < 2) {
#pragma unroll
            for (int j = 0; j < 8; j++)
                b.u[j] = f2bits(We[(size_t)(quad * 8 + j) * HC + col]);
        } else {
#pragma unroll
            for (int j = 0; j < 8; j++) b.u[j] = 0;
        }
        float attc = att[col];
        size_t coff = (size_t)ct * 128;       // ct*64 channels * 2 bytes

#pragma unroll
        for (int t = 0; t < 4; t++) {
            floatx4 c = {0.f, 0.f, 0.f, 0.f};
            c = __builtin_amdgcn_mfma_f32_16x16x32_bf16(afr[t], b.v, c, 0, 0, 0);
#pragma unroll
            for (int r = 0; r < 4; r++) {
                unsigned short ul = *(const unsigned short*)((const char*)xl + xla[t * 4 + r] + coff);
                unsigned short ur = *(const unsigned short*)((const char*)xr + xra[t * 4 + r] + coff);
                float v = c[r] + bits2f(ul) + bits2f(ur);
                v = v > 0.f ? v : 0.2f * v;
                facc[t * 4 + r] += v * attc;
            }
        }

        if ((ct % FE) == FE - 1) {
            int h = ct / FE;
#pragma unroll
            for (int i = 0; i < 16; i++) {
                float v = facc[i];
                v += __shfl_xor(v, 1, 64);
                v += __shfl_xor(v, 2, 64);
                v += __shfl_xor(v, 4, 64);
                v += __shfl_xor(v, 8, 64);
                if (l15 == 0) {
                    int le = 16 * (i >> 2) + quad * 4 + (i & 3);
                    atomicAdd(&logit_s[le * 4 + h], v);
                }
                facc[i] = 0.f;
            }
        }
    }
    __syncthreads();
    logits[(size_t)e0 * 4 + tid] = logit_s[tid];
}

// ---------------- CSR build ----------------
__global__ void hist_kernel(const int* __restrict__ ei, int* __restrict__ counts, int E) {
    int e = blockIdx.x * blockDim.x + threadIdx.x;
    if (e < E) atomicAdd(&counts[ei[E + e]], 1);
}

__global__ __launch_bounds__(1024) void scan_kernel(
    const int* __restrict__ counts, int* __restrict__ offsets,
    int* __restrict__ woff, int N) {
    __shared__ int partial[1024];
    int tid = threadIdx.x;
    const int CH = (N + 1023) >> 10;
    int b0 = tid * CH;
    int s = 0;
    for (int i = 0; i < CH; i++) { int idx = b0 + i; if (idx < N) s += counts[idx]; }
    partial[tid] = s;
    __syncthreads();
    if (tid == 0) {
        int acc = 0;
        for (int i = 0; i < 1024; i++) { int t = partial[i]; partial[i] = acc; acc += t; }
        offsets[N] = acc;
    }
    __syncthreads();
    int run = partial[tid];
    for (int i = 0; i < CH; i++) {
        int idx = b0 + i;
        if (idx < N) { offsets[idx] = run; woff[idx] = run; run += counts[idx]; }
    }
}

__global__ void scatter_kernel(const int* __restrict__ ei, int* __restrict__ woff,
                               int* __restrict__ perm, int E) {
    int e = blockIdx.x * blockDim.x + threadIdx.x;
    if (e < E) {
        int slot = atomicAdd(&woff[ei[E + e]], 1);
        perm[slot] = e;
    }
}

// ---------------- per-node softmax + gather-aggregate + bias + relu ----------
template<int HC, bool OUT_BF16>
__global__ __launch_bounds__(256) void node_agg_kernel(
    const unsigned short* __restrict__ xl, const float* __restrict__ logits,
    const int* __restrict__ ei, const int* __restrict__ offsets,
    const int* __restrict__ perm, const float* __restrict__ bias,
    void* __restrict__ outv, int E) {
    constexpr int V = HC / 256;   // 4 or 1
    int n = blockIdx.x, tid = threadIdx.x;
    int o0 = offsets[n];
    int deg = offsets[n + 1] - o0;
    __shared__ float s_m[4], s_s[4];
    int h = tid >> 6, lane = tid & 63;

    // phase 1: per-head max & sum(exp); wave w handles head w
    float m = -3.0e38f;
    for (int i = lane; i < deg; i += 64) {
        int e = perm[o0 + i];
        m = fmaxf(m, logits[(size_t)e * 4 + h]);
    }
#pragma unroll
    for (int off = 32; off > 0; off >>= 1) m = fmaxf(m, __shfl_down(m, off, 64));
    m = __shfl(m, 0, 64);
    float s = 0.f;
    for (int i = lane; i < deg; i += 64) {
        int e = perm[o0 + i];
        s += expf(logits[(size_t)e * 4 + h] - m);
    }
#pragma unroll
    for (int off = 32; off > 0; off >>= 1) s += __shfl_down(s, off, 64);
    if (lane == 0) { s_m[h] = m; s_s[h] = s; }
    __syncthreads();

    float mh = s_m[h];
    float inv = 1.f / (s_s[h] + 1e-16f);
    int c0 = tid * V;
    float acc[V];
#pragma unroll
    for (int v = 0; v < V; v++) acc[v] = bias[c0 + v];

    for (int i = 0; i < deg; i++) {
        int e = perm[o0 + i];
        int src = ei[e];
        float alpha = expf(logits[(size_t)e * 4 + h] - mh) * inv;
        unsigned short us[V];
        if (V == 4) *(ushort4*)us = *(const ushort4*)&xl[(size_t)src * HC + c0];
        else us[0] = xl[(size_t)src * HC + c0];
#pragma unroll
        for (int v = 0; v < V; v++) acc[v] += alpha * bits2f(us[v]);
    }

    if (OUT_BF16) {
        unsigned short* o = (unsigned short*)outv;
        if (V == 4) {
            ushort4 u;
            u.x = f2bits(fmaxf(acc[0], 0.f));
            u.y = f2bits(fmaxf(acc[1], 0.f));
            u.z = f2bits(fmaxf(acc[2], 0.f));
            u.w = f2bits(fmaxf(acc[3], 0.f));
            *(ushort4*)&o[(size_t)n * HC + c0] = u;
        } else {
            o[(size_t)n * HC + c0] = f2bits(fmaxf(acc[0], 0.f));
        }
    } else {
        float* o = (float*)outv;
#pragma unroll
        for (int v = 0; v < V; v++) o[(size_t)n * HC + c0 + v] = fmaxf(acc[v], 0.f);
    }
}

// ---------------- master-node indices ----------------
__global__ void compute_last_kernel(const int* __restrict__ n_nodes, int* __restrict__ lastidx, int B) {
    if (blockIdx.x == 0 && threadIdx.x == 0) {
        int s = 0;
        for (int b = 0; b < B; b++) { s += n_nodes[b]; lastidx[b] = s - 1; }
    }
}

// ---------------- MLP head ----------------
__global__ __launch_bounds__(64) void mlp_head_kernel(
    const float* __restrict__ h2, const int* __restrict__ lastidx,
    const float* __restrict__ w1, const float* __restrict__ b1,
    const float* __restrict__ w2, const float* __restrict__ b2,
    float* __restrict__ out) {
    int b = blockIdx.x, tid = threadIdx.x;
    __shared__ float mast[256];
    int node = lastidx[b];
    for (int i = tid; i < 256; i += 64) mast[i] = h2[(size_t)node * 256 + i];
    __syncthreads();
    float z = 0.f;
    for (int k = 0; k < 256; k++) z += mast[k] * w1[k * 64 + tid];
    z += b1[tid];
    z = z > 0.f ? z : 0.f;
    float p = z * w2[tid];
#pragma unroll
    for (int off = 32; off > 0; off >>= 1) p += __shfl_down(p, off, 64);
    if (tid == 0) out[b] = p + b2[0];
}

extern "C" void kernel_launch(void* const* d_in, const int* in_sizes, int n_in,
                              void* d_out, int out_size, void* d_ws, size_t ws_size,
                              hipStream_t stream) {
    const float* x     = (const float*)d_in[0];
    const int*   ei    = (const int*)d_in[1];
    const float* eattr = (const float*)d_in[2];
    const int*   nnod  = (const int*)d_in[3];
    const float* Wl1 = (const float*)d_in[4];
    const float* bl1 = (const float*)d_in[5];
    const float* Wr1 = (const float*)d_in[6];
    const float* br1 = (const float*)d_in[7];
    const float* We1 = (const float*)d_in[8];
    const float* att1= (const float*)d_in[9];
    const float* b1  = (const float*)d_in[10];
    const float* Wl2 = (const float*)d_in[11];
    const float* bl2 = (const float*)d_in[12];
    const float* Wr2 = (const float*)d_in[13];
    const float* br2 = (const float*)d_in[14];
    const float* We2 = (const float*)d_in[15];
    const float* att2= (const float*)d_in[16];
    const float* b2  = (const float*)d_in[17];
    const float* fc1w= (const float*)d_in[18];
    const float* fc1b= (const float*)d_in[19];
    const float* fc2w= (const float*)d_in[20];
    const float* fc2b= (const float*)d_in[21];
    float* out = (float*)d_out;

    const int N = NN, E = EE, B = BB;

    // ---------- workspace layout (peak ~224 MB) ----------
    char* base = (char*)d_ws;
    const size_t NB1 = (size_t)N * 1024 * 2;                  // 102,236,160 B
    // region A [0, NB1): xl1 bf16  | layer2: xl2 bf16 (N*256), xr2 bf16 (N*256), h2 f32 (N*256)
    unsigned short* xl1 = (unsigned short*)base;
    unsigned short* xl2 = (unsigned short*)base;
    unsigned short* xr2 = (unsigned short*)(base + (size_t)N * 256 * 2);
    float*          h2  = (float*)(base + (size_t)N * 256 * 4);
    // region B [NB1, 2*NB1): xr1 bf16 | h1 bf16 overlays xr1 after edge_score1
    unsigned short* xr1 = (unsigned short*)(base + NB1);
    unsigned short* h1  = (unsigned short*)(base + NB1);
    // tail
    char* t = base + 2 * NB1;
    float* logits = (float*)t;        t += (size_t)E * 4 * sizeof(float);
    int* counts   = (int*)t;          t += (size_t)N * sizeof(int);
    int* offsets  = (int*)t;          t += (size_t)(N + 1) * sizeof(int);
    int* woff     = (int*)t;          t += (size_t)N * sizeof(int);
    int* perm     = (int*)t;          t += (size_t)E * sizeof(int);
    int* lastidx  = (int*)t;          t += (size_t)B * sizeof(int);
    unsigned short* xb   = (unsigned short*)t; t += (size_t)N * 128 * 2;
    unsigned short* wl1b = (unsigned short*)t; t += (size_t)128 * 1024 * 2;
    unsigned short* wr1b = (unsigned short*)t; t += (size_t)128 * 1024 * 2;
    unsigned short* wl2b = (unsigned short*)t; t += (size_t)1024 * 256 * 2;
    unsigned short* wr2b = (unsigned short*)t; t += (size_t)1024 * 256 * 2;
    size_t required = (size_t)(t - base);
    if (ws_size < required) return;   // guard: absmax-fail instead of abort

    dim3 blk(256);

    // ---------- CSR build ----------
    zero_int_kernel<<<(N + 255) / 256, blk, 0, stream>>>(counts, N);
    hist_kernel<<<(E + 255) / 256, blk, 0, stream>>>(ei, counts, E);
    scan_kernel<<<1, 1024, 0, stream>>>(counts, offsets, woff, N);
    scatter_kernel<<<(E + 255) / 256, blk, 0, stream>>>(ei, woff, perm, E);

    // ---------- bf16 conversions ----------
    convert_bf16_kernel<<<(N * 128 + 255) / 256, blk, 0, stream>>>(x, xb, N * 128);
    convert_bf16_kernel<<<(128 * 1024 + 255) / 256, blk, 0, stream>>>(Wl1, wl1b, 128 * 1024);
    convert_bf16_kernel<<<(128 * 1024 + 255) / 256, blk, 0, stream>>>(Wr1, wr1b, 128 * 1024);
    convert_bf16_kernel<<<(1024 * 256 + 255) / 256, blk, 0, stream>>>(Wl2, wl2b, 1024 * 256);
    convert_bf16_kernel<<<(1024 * 256 + 255) / 256, blk, 0, stream>>>(Wr2, wr2b, 1024 * 256);

    // ---------- layer 1 ----------
    {
        dim3 g1(1024 / 128, N / 128);
        mfma_gemm_kernel<<<g1, blk, 0, stream>>>(xb, wl1b, bl1, xl1, N, 128, 1024);
        mfma_gemm_kernel<<<g1, blk, 0, stream>>>(xb, wr1b, br1, xr1, N, 128, 1024);
    }
    edge_score_mfma_kernel<1024><<<E / 64, blk, 0, stream>>>(xl1, xr1, eattr, We1, att1, ei, logits, E);
    node_agg_kernel<1024, true><<<N, blk, 0, stream>>>(xl1, logits, ei, offsets, perm, b1, h1, E);

    // ---------- layer 2 ----------
    {
        dim3 g2(256 / 128, N / 128);
        mfma_gemm_kernel<<<g2, blk, 0, stream>>>(h1, wl2b, bl2, xl2, N, 1024, 256);
        mfma_gemm_kernel<<<g2, blk, 0, stream>>>(h1, wr2b, br2, xr2, N, 1024, 256);
    }
    edge_score_mfma_kernel<256><<<E / 64, blk, 0, stream>>>(xl2, xr2, eattr, We2, att2, ei, logits, E);
    node_agg_kernel<256, false><<<N, blk, 0, stream>>>(xl2, logits, ei, offsets, perm, b2, h2, E);

    // ---------- head ----------
    compute_last_kernel<<<1, 64, 0, stream>>>(nnod, lastidx, B);
    mlp_head_kernel<<<B, 64, 0, stream>>>(h2, lastidx, fc1w, fc1b, fc2w, fc2b, out);
}

// Round 6
// 1285.145 us; speedup vs baseline: 1.0343x; 1.0343x over previous
//
#include <hip/hip_runtime.h>
#include <hip/hip_bf16.h>
#include <cmath>

#define NN 49920
#define EE 200000
#define BB 128

typedef __attribute__((ext_vector_type(8))) short short8;
typedef __attribute__((ext_vector_type(4))) float floatx4;

__device__ __forceinline__ float bits2f(unsigned short u) {
    union { unsigned int i; float f; } c; c.i = ((unsigned int)u) << 16; return c.f;
}
__device__ __forceinline__ unsigned short f2bits(float f) {
    union { float f; unsigned int i; } c; c.f = f;
    unsigned int x = c.i;
    return (unsigned short)((x + 0x7fffu + ((x >> 16) & 1u)) >> 16);   // RNE, finite inputs
}

// ---------------- small utility kernels ----------------
__global__ void zero_int_kernel(int* __restrict__ p, int n) {
    int i = blockIdx.x * blockDim.x + threadIdx.x;
    if (i < n) p[i] = 0;
}

__global__ void convert_bf16_kernel(const float* __restrict__ src, unsigned short* __restrict__ dst, int n) {
    int i = blockIdx.x * blockDim.x + threadIdx.x;
    if (i < n) dst[i] = f2bits(src[i]);
}

// We [16][HC] f32 -> WeT [HC][16] bf16 (transposed, for MFMA B-frag 16B loads)
__global__ void convert_WeT_kernel(const float* __restrict__ We, unsigned short* __restrict__ WeT, int HC) {
    int i = blockIdx.x * blockDim.x + threadIdx.x;
    if (i < HC * 16) {
        int col = i >> 4, k = i & 15;
        WeT[i] = f2bits(We[k * HC + col]);
    }
}

// ---------------- bf16 MFMA GEMM: C(bf16) = A@W + bias ----------------
// A [M,K] bf16 row-major, W [K,N] bf16 row-major, bias [N] f32, C [M,N] bf16.
// Block: 256 thr = 4 waves, 128x128 C-tile (waves 2x2 of 64x64), BK=32.
#define LDK 40   // padded LDS k-stride in ushorts (80B: keeps b128 16B-aligned, 2-way banks)

__global__ __launch_bounds__(256) void mfma_gemm_kernel(
    const unsigned short* __restrict__ A, const unsigned short* __restrict__ W,
    const float* __restrict__ bias, unsigned short* __restrict__ C,
    int M, int K, int N) {
    __shared__ unsigned short As[128 * LDK];
    __shared__ unsigned short Bt[128 * LDK];   // B transposed: Bt[n][k]
    int tid = threadIdx.x;
    int lane = tid & 63, wid = tid >> 6;
    int gm0 = blockIdx.y * 128, gn0 = blockIdx.x * 128;
    int wm = (wid & 1) * 64, wn = (wid >> 1) * 64;
    int row15 = lane & 15, quad = lane >> 4;

    floatx4 acc[4][4];
#pragma unroll
    for (int i = 0; i < 4; i++)
#pragma unroll
        for (int j = 0; j < 4; j++)
#pragma unroll
            for (int r = 0; r < 4; r++) acc[i][j][r] = 0.f;

    for (int k0 = 0; k0 < K; k0 += 32) {
        __syncthreads();
        {
            int idx = tid;
#pragma unroll
            for (int l = 0; l < 2; l++, idx += 256) {
                int r = idx >> 2;
                int kp = (idx & 3) * 8;
                *(uint4*)&As[r * LDK + kp] = *(const uint4*)&A[(size_t)(gm0 + r) * K + k0 + kp];
            }
        }
        {
            int idx = tid;
#pragma unroll
            for (int l = 0; l < 2; l++, idx += 256) {
                int kr = idx >> 4;
                int cg = (idx & 15) * 8;
                union { uint4 v; unsigned short u[8]; } w;
                w.v = *(const uint4*)&W[(size_t)(k0 + kr) * N + gn0 + cg];
#pragma unroll
                for (int j = 0; j < 8; j++) Bt[(cg + j) * LDK + kr] = w.u[j];
            }
        }
        __syncthreads();
        short8 af[4], bfr[4];
#pragma unroll
        for (int i = 0; i < 4; i++)
            af[i] = *(const short8*)&As[(wm + 16 * i + row15) * LDK + quad * 8];
#pragma unroll
        for (int j = 0; j < 4; j++)
            bfr[j] = *(const short8*)&Bt[(wn + 16 * j + row15) * LDK + quad * 8];
#pragma unroll
        for (int i = 0; i < 4; i++)
#pragma unroll
            for (int j = 0; j < 4; j++)
                acc[i][j] = __builtin_amdgcn_mfma_f32_16x16x32_bf16(af[i], bfr[j], acc[i][j], 0, 0, 0);
    }

    int colb = gn0 + wn + row15;
#pragma unroll
    for (int i = 0; i < 4; i++) {
#pragma unroll
        for (int j = 0; j < 4; j++) {
            int col = colb + 16 * j;
            float bv = bias[col];
#pragma unroll
            for (int r = 0; r < 4; r++) {
                int rrow = gm0 + wm + 16 * i + quad * 4 + r;
                C[(size_t)rrow * N + col] = f2bits(acc[i][j][r] + bv);
            }
        }
    }
}

// ---------------- edge scoring v3: MFMA ef->LDS + coalesced phase 2 ----------
// 16 edges/block (E = 16*12500 exactly). Phase 1: ef=eattr@We via MFMA into LDS
// (bf16, stride HC+8). Phase 2: thread owns channels c0=tid*J across ALL edges
// -> ushort4 coalesced xl/xr loads; wave w = head w; shuffle-reduce per edge.
template<int HC>
__global__ __launch_bounds__(256) void edge_score_v3_kernel(
    const unsigned short* __restrict__ xl, const unsigned short* __restrict__ xr,
    const float* __restrict__ eattr, const unsigned short* __restrict__ WeT,
    const float* __restrict__ att, const int* __restrict__ ei,
    float* __restrict__ logits, int E) {
    constexpr int J = HC / 256;          // 4 (L1) or 1 (L2)
    constexpr int LDE = HC + 8;          // ushort row stride (16B-aligned rows)
    __shared__ unsigned short ef_s[16 * LDE];
    __shared__ int src_s[16], dst_s[16];
    __shared__ float logit_s[64];

    int tid = threadIdx.x;
    int e0 = blockIdx.x * 16;
    int lane = tid & 63, w = tid >> 6;
    int l15 = lane & 15, quad = lane >> 4;

    if (tid < 16) { src_s[tid] = ei[e0 + tid]; dst_s[tid] = ei[E + e0 + tid]; }

    // A-frag: eattr rows (16 edges x 16 k), K zero-padded to 32
    union { short8 v; unsigned short u[8]; } a;
    if (quad < 2) {
        const float* ap = &eattr[(size_t)(e0 + l15) * 16 + quad * 8];
        float4 a0 = *(const float4*)ap;
        float4 a1 = *(const float4*)(ap + 4);
        a.u[0] = f2bits(a0.x); a.u[1] = f2bits(a0.y); a.u[2] = f2bits(a0.z); a.u[3] = f2bits(a0.w);
        a.u[4] = f2bits(a1.x); a.u[5] = f2bits(a1.y); a.u[6] = f2bits(a1.z); a.u[7] = f2bits(a1.w);
    } else {
#pragma unroll
        for (int j = 0; j < 8; j++) a.u[j] = 0;
    }

    // Phase 1: wave w computes col-tiles w, w+4, ... -> ef_s
    for (int t = w; t < HC / 16; t += 4) {
        int col = t * 16 + l15;
        union { short8 v; unsigned short u[8]; } b;
        if (quad < 2) *(uint4*)b.u = *(const uint4*)&WeT[(size_t)col * 16 + quad * 8];
        else {
#pragma unroll
            for (int j = 0; j < 8; j++) b.u[j] = 0;
        }
        floatx4 c = {0.f, 0.f, 0.f, 0.f};
        c = __builtin_amdgcn_mfma_f32_16x16x32_bf16(a.v, b.v, c, 0, 0, 0);
#pragma unroll
        for (int r = 0; r < 4; r++)
            ef_s[(quad * 4 + r) * LDE + col] = f2bits(c[r]);
    }
    __syncthreads();

    // Phase 2
    int c0 = tid * J;
    float attr[J];
#pragma unroll
    for (int j = 0; j < J; j++) attr[j] = att[c0 + j];

#pragma unroll 4
    for (int e = 0; e < 16; e++) {
        int src = src_s[e], dst = dst_s[e];
        unsigned short ul[J], ur[J], uf[J];
        if (J == 4) {
            *(ushort4*)ul = *(const ushort4*)&xl[(size_t)src * HC + c0];
            *(ushort4*)ur = *(const ushort4*)&xr[(size_t)dst * HC + c0];
            *(ushort4*)uf = *(const ushort4*)&ef_s[e * LDE + c0];
        } else {
            ul[0] = xl[(size_t)src * HC + c0];
            ur[0] = xr[(size_t)dst * HC + c0];
            uf[0] = ef_s[e * LDE + c0];
        }
        float part = 0.f;
#pragma unroll
        for (int j = 0; j < J; j++) {
            float v = bits2f(ul[j]) + bits2f(ur[j]) + bits2f(uf[j]);
            v = v > 0.f ? v : 0.2f * v;
            part += v * attr[j];
        }
#pragma unroll
        for (int off = 32; off > 0; off >>= 1) part += __shfl_down(part, off, 64);
        if (lane == 0) logit_s[e * 4 + w] = part;
    }
    __syncthreads();
    if (tid < 64) logits[(size_t)e0 * 4 + tid] = logit_s[tid];
}

// ---------------- CSR build ----------------
__global__ void hist_kernel(const int* __restrict__ ei, int* __restrict__ counts, int E) {
    int e = blockIdx.x * blockDim.x + threadIdx.x;
    if (e < E) atomicAdd(&counts[ei[E + e]], 1);
}

__global__ __launch_bounds__(1024) void scan_kernel(
    const int* __restrict__ counts, int* __restrict__ offsets,
    int* __restrict__ woff, int N) {
    __shared__ int partial[1024];
    int tid = threadIdx.x;
    const int CH = (N + 1023) >> 10;
    int b0 = tid * CH;
    int s = 0;
    for (int i = 0; i < CH; i++) { int idx = b0 + i; if (idx < N) s += counts[idx]; }
    partial[tid] = s;
    __syncthreads();
    if (tid == 0) {
        int acc = 0;
        for (int i = 0; i < 1024; i++) { int t = partial[i]; partial[i] = acc; acc += t; }
        offsets[N] = acc;
    }
    __syncthreads();
    int run = partial[tid];
    for (int i = 0; i < CH; i++) {
        int idx = b0 + i;
        if (idx < N) { offsets[idx] = run; woff[idx] = run; run += counts[idx]; }
    }
}

__global__ void scatter_kernel(const int* __restrict__ ei, int* __restrict__ woff,
                               int* __restrict__ perm, int E) {
    int e = blockIdx.x * blockDim.x + threadIdx.x;
    if (e < E) {
        int slot = atomicAdd(&woff[ei[E + e]], 1);
        perm[slot] = e;
    }
}

// ---------------- per-node softmax + gather-aggregate + bias + relu ----------
template<int HC, bool OUT_BF16>
__global__ __launch_bounds__(256) void node_agg_kernel(
    const unsigned short* __restrict__ xl, const float* __restrict__ logits,
    const int* __restrict__ ei, const int* __restrict__ offsets,
    const int* __restrict__ perm, const float* __restrict__ bias,
    void* __restrict__ outv, int E) {
    constexpr int V = HC / 256;   // 4 or 1
    int n = blockIdx.x, tid = threadIdx.x;
    int o0 = offsets[n];
    int deg = offsets[n + 1] - o0;
    __shared__ float s_m[4], s_s[4];
    int h = tid >> 6, lane = tid & 63;

    float m = -3.0e38f;
    for (int i = lane; i < deg; i += 64) {
        int e = perm[o0 + i];
        m = fmaxf(m, logits[(size_t)e * 4 + h]);
    }
#pragma unroll
    for (int off = 32; off > 0; off >>= 1) m = fmaxf(m, __shfl_down(m, off, 64));
    m = __shfl(m, 0, 64);
    float s = 0.f;
    for (int i = lane; i < deg; i += 64) {
        int e = perm[o0 + i];
        s += expf(logits[(size_t)e * 4 + h] - m);
    }
#pragma unroll
    for (int off = 32; off > 0; off >>= 1) s += __shfl_down(s, off, 64);
    if (lane == 0) { s_m[h] = m; s_s[h] = s; }
    __syncthreads();

    float mh = s_m[h];
    float inv = 1.f / (s_s[h] + 1e-16f);
    int c0 = tid * V;
    float acc[V];
#pragma unroll
    for (int v = 0; v < V; v++) acc[v] = bias[c0 + v];

    for (int i = 0; i < deg; i++) {
        int e = perm[o0 + i];
        int src = ei[e];
        float alpha = expf(logits[(size_t)e * 4 + h] - mh) * inv;
        unsigned short us[V];
        if (V == 4) *(ushort4*)us = *(const ushort4*)&xl[(size_t)src * HC + c0];
        else us[0] = xl[(size_t)src * HC + c0];
#pragma unroll
        for (int v = 0; v < V; v++) acc[v] += alpha * bits2f(us[v]);
    }

    if (OUT_BF16) {
        unsigned short* o = (unsigned short*)outv;
        if (V == 4) {
            ushort4 u;
            u.x = f2bits(fmaxf(acc[0], 0.f));
            u.y = f2bits(fmaxf(acc[1], 0.f));
            u.z = f2bits(fmaxf(acc[2], 0.f));
            u.w = f2bits(fmaxf(acc[3], 0.f));
            *(ushort4*)&o[(size_t)n * HC + c0] = u;
        } else {
            o[(size_t)n * HC + c0] = f2bits(fmaxf(acc[0], 0.f));
        }
    } else {
        float* o = (float*)outv;
#pragma unroll
        for (int v = 0; v < V; v++) o[(size_t)n * HC + c0 + v] = fmaxf(acc[v], 0.f);
    }
}

// ---------------- master-node indices ----------------
__global__ void compute_last_kernel(const int* __restrict__ n_nodes, int* __restrict__ lastidx, int B) {
    if (blockIdx.x == 0 && threadIdx.x == 0) {
        int s = 0;
        for (int b = 0; b < B; b++) { s += n_nodes[b]; lastidx[b] = s - 1; }
    }
}

// ---------------- MLP head ----------------
__global__ __launch_bounds__(64) void mlp_head_kernel(
    const float* __restrict__ h2, const int* __restrict__ lastidx,
    const float* __restrict__ w1, const float* __restrict__ b1,
    const float* __restrict__ w2, const float* __restrict__ b2,
    float* __restrict__ out) {
    int b = blockIdx.x, tid = threadIdx.x;
    __shared__ float mast[256];
    int node = lastidx[b];
    for (int i = tid; i < 256; i += 64) mast[i] = h2[(size_t)node * 256 + i];
    __syncthreads();
    float z = 0.f;
    for (int k = 0; k < 256; k++) z += mast[k] * w1[k * 64 + tid];
    z += b1[tid];
    z = z > 0.f ? z : 0.f;
    float p = z * w2[tid];
#pragma unroll
    for (int off = 32; off > 0; off >>= 1) p += __shfl_down(p, off, 64);
    if (tid == 0) out[b] = p + b2[0];
}

extern "C" void kernel_launch(void* const* d_in, const int* in_sizes, int n_in,
                              void* d_out, int out_size, void* d_ws, size_t ws_size,
                              hipStream_t stream) {
    const float* x     = (const float*)d_in[0];
    const int*   ei    = (const int*)d_in[1];
    const float* eattr = (const float*)d_in[2];
    const int*   nnod  = (const int*)d_in[3];
    const float* Wl1 = (const float*)d_in[4];
    const float* bl1 = (const float*)d_in[5];
    const float* Wr1 = (const float*)d_in[6];
    const float* br1 = (const float*)d_in[7];
    const float* We1 = (const float*)d_in[8];
    const float* att1= (const float*)d_in[9];
    const float* b1  = (const float*)d_in[10];
    const float* Wl2 = (const float*)d_in[11];
    const float* bl2 = (const float*)d_in[12];
    const float* Wr2 = (const float*)d_in[13];
    const float* br2 = (const float*)d_in[14];
    const float* We2 = (const float*)d_in[15];
    const float* att2= (const float*)d_in[16];
    const float* b2  = (const float*)d_in[17];
    const float* fc1w= (const float*)d_in[18];
    const float* fc1b= (const float*)d_in[19];
    const float* fc2w= (const float*)d_in[20];
    const float* fc2b= (const float*)d_in[21];
    float* out = (float*)d_out;

    const int N = NN, E = EE, B = BB;

    // ---------- workspace layout (peak ~224 MB) ----------
    char* base = (char*)d_ws;
    const size_t NB1 = (size_t)N * 1024 * 2;                  // 102,236,160 B
    unsigned short* xl1 = (unsigned short*)base;
    unsigned short* xl2 = (unsigned short*)base;
    unsigned short* xr2 = (unsigned short*)(base + (size_t)N * 256 * 2);
    float*          h2  = (float*)(base + (size_t)N * 256 * 4);
    unsigned short* xr1 = (unsigned short*)(base + NB1);
    unsigned short* h1  = (unsigned short*)(base + NB1);
    char* t = base + 2 * NB1;
    float* logits = (float*)t;        t += (size_t)E * 4 * sizeof(float);
    int* counts   = (int*)t;          t += (size_t)N * sizeof(int);
    int* offsets  = (int*)t;          t += (size_t)(N + 1) * sizeof(int);
    int* woff     = (int*)t;          t += (size_t)N * sizeof(int);
    int* perm     = (int*)t;          t += (size_t)E * sizeof(int);
    int* lastidx  = (int*)t;          t += (size_t)B * sizeof(int);
    unsigned short* xb   = (unsigned short*)t; t += (size_t)N * 128 * 2;
    unsigned short* wl1b = (unsigned short*)t; t += (size_t)128 * 1024 * 2;
    unsigned short* wr1b = (unsigned short*)t; t += (size_t)128 * 1024 * 2;
    unsigned short* wl2b = (unsigned short*)t; t += (size_t)1024 * 256 * 2;
    unsigned short* wr2b = (unsigned short*)t; t += (size_t)1024 * 256 * 2;
    unsigned short* weT1 = (unsigned short*)t; t += (size_t)1024 * 16 * 2;
    unsigned short* weT2 = (unsigned short*)t; t += (size_t)256 * 16 * 2;
    size_t required = (size_t)(t - base);
    if (ws_size < required) return;   // guard: absmax-fail instead of abort

    dim3 blk(256);

    // ---------- CSR build ----------
    zero_int_kernel<<<(N + 255) / 256, blk, 0, stream>>>(counts, N);
    hist_kernel<<<(E + 255) / 256, blk, 0, stream>>>(ei, counts, E);
    scan_kernel<<<1, 1024, 0, stream>>>(counts, offsets, woff, N);
    scatter_kernel<<<(E + 255) / 256, blk, 0, stream>>>(ei, woff, perm, E);

    // ---------- bf16 conversions ----------
    convert_bf16_kernel<<<(N * 128 + 255) / 256, blk, 0, stream>>>(x, xb, N * 128);
    convert_bf16_kernel<<<(128 * 1024 + 255) / 256, blk, 0, stream>>>(Wl1, wl1b, 128 * 1024);
    convert_bf16_kernel<<<(128 * 1024 + 255) / 256, blk, 0, stream>>>(Wr1, wr1b, 128 * 1024);
    convert_bf16_kernel<<<(1024 * 256 + 255) / 256, blk, 0, stream>>>(Wl2, wl2b, 1024 * 256);
    convert_bf16_kernel<<<(1024 * 256 + 255) / 256, blk, 0, stream>>>(Wr2, wr2b, 1024 * 256);
    convert_WeT_kernel<<<(1024 * 16 + 255) / 256, blk, 0, stream>>>(We1, weT1, 1024);
    convert_WeT_kernel<<<(256 * 16 + 255) / 256, blk, 0, stream>>>(We2, weT2, 256);

    // ---------- layer 1 ----------
    {
        dim3 g1(1024 / 128, N / 128);
        mfma_gemm_kernel<<<g1, blk, 0, stream>>>(xb, wl1b, bl1, xl1, N, 128, 1024);
        mfma_gemm_kernel<<<g1, blk, 0, stream>>>(xb, wr1b, br1, xr1, N, 128, 1024);
    }
    edge_score_v3_kernel<1024><<<E / 16, blk, 0, stream>>>(xl1, xr1, eattr, weT1, att1, ei, logits, E);
    node_agg_kernel<1024, true><<<N, blk, 0, stream>>>(xl1, logits, ei, offsets, perm, b1, h1, E);

    // ---------- layer 2 ----------
    {
        dim3 g2(256 / 128, N / 128);
        mfma_gemm_kernel<<<g2, blk, 0, stream>>>(h1, wl2b, bl2, xl2, N, 1024, 256);
        mfma_gemm_kernel<<<g2, blk, 0, stream>>>(h1, wr2b, br2, xr2, N, 1024, 256);
    }
    edge_score_v3_kernel<256><<<E / 16, blk, 0, stream>>>(xl2, xr2, eattr, weT2, att2, ei, logits, E);
    node_agg_kernel<256, false><<<N, blk, 0, stream>>>(xl2, logits, ei, offsets, perm, b2, h2, E);

    // ---------- head ----------
    compute_last_kernel<<<1, 64, 0, stream>>>(nnod, lastidx, B);
    mlp_head_kernel<<<B, 64, 0, stream>>>(h2, lastidx, fc1w, fc1b, fc2w, fc2b, out);
}

// Round 7
// 1017.874 us; speedup vs baseline: 1.3059x; 1.2626x over previous
//
#include <hip/hip_runtime.h>
#include <hip/hip_bf16.h>
#include <cmath>

#define NN 49920
#define EE 200000
#define BB 128

typedef __attribute__((ext_vector_type(8))) short short8;
typedef __attribute__((ext_vector_type(4))) float floatx4;

__device__ __forceinline__ float bits2f(unsigned short u) {
    union { unsigned int i; float f; } c; c.i = ((unsigned int)u) << 16; return c.f;
}
__device__ __forceinline__ unsigned short f2bits(float f) {
    union { float f; unsigned int i; } c; c.f = f;
    unsigned int x = c.i;
    return (unsigned short)((x + 0x7fffu + ((x >> 16) & 1u)) >> 16);   // RNE, finite inputs
}

// ---------------- small utility kernels ----------------
__global__ void zero_int_kernel(int* __restrict__ p, int n) {
    int i = blockIdx.x * blockDim.x + threadIdx.x;
    if (i < n) p[i] = 0;
}

__global__ void convert_bf16_kernel(const float* __restrict__ src, unsigned short* __restrict__ dst, int n) {
    int i = blockIdx.x * blockDim.x + threadIdx.x;
    if (i < n) dst[i] = f2bits(src[i]);
}

// W [K][N] f32 -> WT [N][K] bf16
__global__ void convert_wt_kernel(const float* __restrict__ W, unsigned short* __restrict__ WT, int K, int N) {
    int i = blockIdx.x * blockDim.x + threadIdx.x;
    if (i < K * N) {
        int n = i / K, k = i - n * K;
        WT[i] = f2bits(W[(size_t)k * N + n]);
    }
}

// We [16][HC] f32 -> WeT [HC][16] bf16
__global__ void convert_WeT_kernel(const float* __restrict__ We, unsigned short* __restrict__ WeT, int HC) {
    int i = blockIdx.x * blockDim.x + threadIdx.x;
    if (i < HC * 16) {
        int col = i >> 4, k = i & 15;
        WeT[i] = f2bits(We[k * HC + col]);
    }
}

// ---------------- bf16 MFMA GEMM (B^T input): C = A @ WT^T + bias ----------
// A [M,K] bf16 row-major, WT [N,K] bf16 row-major, bias[N] f32, C [M,N] bf16.
// 256 thr = 4 waves, 128x128 tile (waves 2x2 of 64x64), BK=32, uint4 staging.
__global__ __launch_bounds__(256) void mfma_gemm_bt_kernel(
    const unsigned short* __restrict__ A, const unsigned short* __restrict__ WT,
    const float* __restrict__ bias, unsigned short* __restrict__ C,
    int M, int K, int N) {
    __shared__ unsigned short As[128 * 32];
    __shared__ unsigned short Bs[128 * 32];
    int tid = threadIdx.x;
    int lane = tid & 63, wid = tid >> 6;
    int gm0 = blockIdx.y * 128, gn0 = blockIdx.x * 128;
    int wm = (wid & 1) * 64, wn = (wid >> 1) * 64;
    int l15 = lane & 15, quad = lane >> 4;
    int srow = tid >> 2;          // 0..63
    int skp = (tid & 3) * 8;      // 0,8,16,24

    floatx4 acc[4][4];
#pragma unroll
    for (int i = 0; i < 4; i++)
#pragma unroll
        for (int j = 0; j < 4; j++)
#pragma unroll
            for (int r = 0; r < 4; r++) acc[i][j][r] = 0.f;

    for (int k0 = 0; k0 < K; k0 += 32) {
        __syncthreads();
        *(uint4*)&As[srow * 32 + skp]        = *(const uint4*)&A[(size_t)(gm0 + srow) * K + k0 + skp];
        *(uint4*)&As[(srow + 64) * 32 + skp] = *(const uint4*)&A[(size_t)(gm0 + srow + 64) * K + k0 + skp];
        *(uint4*)&Bs[srow * 32 + skp]        = *(const uint4*)&WT[(size_t)(gn0 + srow) * K + k0 + skp];
        *(uint4*)&Bs[(srow + 64) * 32 + skp] = *(const uint4*)&WT[(size_t)(gn0 + srow + 64) * K + k0 + skp];
        __syncthreads();
        short8 af[4], bfr[4];
#pragma unroll
        for (int i = 0; i < 4; i++)
            af[i] = *(const short8*)&As[(wm + 16 * i + l15) * 32 + quad * 8];
#pragma unroll
        for (int j = 0; j < 4; j++)
            bfr[j] = *(const short8*)&Bs[(wn + 16 * j + l15) * 32 + quad * 8];
#pragma unroll
        for (int i = 0; i < 4; i++)
#pragma unroll
            for (int j = 0; j < 4; j++)
                acc[i][j] = __builtin_amdgcn_mfma_f32_16x16x32_bf16(af[i], bfr[j], acc[i][j], 0, 0, 0);
    }

    int colb = gn0 + wn + l15;
#pragma unroll
    for (int i = 0; i < 4; i++) {
#pragma unroll
        for (int j = 0; j < 4; j++) {
            int col = colb + 16 * j;
            float bv = bias[col];
#pragma unroll
            for (int r = 0; r < 4; r++) {
                int rrow = gm0 + wm + 16 * i + quad * 4 + r;
                C[(size_t)rrow * N + col] = f2bits(acc[i][j][r] + bv);
            }
        }
    }
}

// ---------------- CSR build ----------------
__global__ void hist_kernel(const int* __restrict__ ei, int* __restrict__ counts, int E) {
    int e = blockIdx.x * blockDim.x + threadIdx.x;
    if (e < E) atomicAdd(&counts[ei[E + e]], 1);
}

__global__ __launch_bounds__(1024) void scan_kernel(
    const int* __restrict__ counts, int* __restrict__ offsets,
    int* __restrict__ woff, int N) {
    __shared__ int partial[1024];
    int tid = threadIdx.x;
    const int CH = (N + 1023) >> 10;
    int b0 = tid * CH;
    int s = 0;
    for (int i = 0; i < CH; i++) { int idx = b0 + i; if (idx < N) s += counts[idx]; }
    partial[tid] = s;
    __syncthreads();
    if (tid == 0) {
        int acc = 0;
        for (int i = 0; i < 1024; i++) { int t = partial[i]; partial[i] = acc; acc += t; }
        offsets[N] = acc;
    }
    __syncthreads();
    int run = partial[tid];
    for (int i = 0; i < CH; i++) {
        int idx = b0 + i;
        if (idx < N) { offsets[idx] = run; woff[idx] = run; run += counts[idx]; }
    }
}

// scatter: slot-sorted by dst; also emit srcs/dsts per slot
__global__ void scatter_kernel(const int* __restrict__ ei, int* __restrict__ woff,
                               int* __restrict__ perm, int* __restrict__ srcs,
                               int* __restrict__ dsts, int E) {
    int e = blockIdx.x * blockDim.x + threadIdx.x;
    if (e < E) {
        int d = ei[E + e];
        int slot = atomicAdd(&woff[d], 1);
        perm[slot] = e;
        srcs[slot] = ei[e];
        dsts[slot] = d;
    }
}

// ---------------- edge scoring v4: slot-ordered (dst-sorted) ----------------
// 16 slots/block. Phase 1: ef = eattr[perm[s]] @ We via MFMA -> LDS (bf16).
// Phase 2: thread owns channels c0=tid*J; coalesced xl/xr row reads (xr has
// dst-locality); wave w = head w; logits written at slot position (coalesced
// consumer reads in node_agg).
template<int HC>
__global__ __launch_bounds__(256) void edge_score_v4_kernel(
    const unsigned short* __restrict__ xl, const unsigned short* __restrict__ xr,
    const float* __restrict__ eattr, const unsigned short* __restrict__ WeT,
    const float* __restrict__ att, const int* __restrict__ perm,
    const int* __restrict__ srcs, const int* __restrict__ dsts,
    float* __restrict__ logits, int E) {
    constexpr int J = HC / 256;          // 4 (L1) or 1 (L2)
    constexpr int LDE = HC + 8;
    __shared__ unsigned short ef_s[16 * LDE];
    __shared__ int src_s[16], dst_s[16], e_s[16];
    __shared__ float logit_s[64];

    int tid = threadIdx.x;
    int s0 = blockIdx.x * 16;
    int lane = tid & 63, w = tid >> 6;
    int l15 = lane & 15, quad = lane >> 4;

    if (tid < 16) {
        e_s[tid] = perm[s0 + tid];
        src_s[tid] = srcs[s0 + tid];
        dst_s[tid] = dsts[s0 + tid];
    }
    __syncthreads();

    // A-frag: eattr rows for the 16 slots (gathered; eattr is L2-resident)
    union { short8 v; unsigned short u[8]; } a;
    if (quad < 2) {
        const float* ap = &eattr[(size_t)e_s[l15] * 16 + quad * 8];
        float4 a0 = *(const float4*)ap;
        float4 a1 = *(const float4*)(ap + 4);
        a.u[0] = f2bits(a0.x); a.u[1] = f2bits(a0.y); a.u[2] = f2bits(a0.z); a.u[3] = f2bits(a0.w);
        a.u[4] = f2bits(a1.x); a.u[5] = f2bits(a1.y); a.u[6] = f2bits(a1.z); a.u[7] = f2bits(a1.w);
    } else {
#pragma unroll
        for (int j = 0; j < 8; j++) a.u[j] = 0;
    }

    // Phase 1: ef -> LDS
    for (int t = w; t < HC / 16; t += 4) {
        int col = t * 16 + l15;
        union { short8 v; unsigned short u[8]; } b;
        if (quad < 2) *(uint4*)b.u = *(const uint4*)&WeT[(size_t)col * 16 + quad * 8];
        else {
#pragma unroll
            for (int j = 0; j < 8; j++) b.u[j] = 0;
        }
        floatx4 c = {0.f, 0.f, 0.f, 0.f};
        c = __builtin_amdgcn_mfma_f32_16x16x32_bf16(a.v, b.v, c, 0, 0, 0);
#pragma unroll
        for (int r = 0; r < 4; r++)
            ef_s[(quad * 4 + r) * LDE + col] = f2bits(c[r]);
    }
    __syncthreads();

    // Phase 2
    int c0 = tid * J;
    float attr[J];
#pragma unroll
    for (int j = 0; j < J; j++) attr[j] = att[c0 + j];

#pragma unroll 4
    for (int e = 0; e < 16; e++) {
        int src = src_s[e], dst = dst_s[e];
        unsigned short ul[J], ur[J], uf[J];
        if (J == 4) {
            *(ushort4*)ul = *(const ushort4*)&xl[(size_t)src * HC + c0];
            *(ushort4*)ur = *(const ushort4*)&xr[(size_t)dst * HC + c0];
            *(ushort4*)uf = *(const ushort4*)&ef_s[e * LDE + c0];
        } else {
            ul[0] = xl[(size_t)src * HC + c0];
            ur[0] = xr[(size_t)dst * HC + c0];
            uf[0] = ef_s[e * LDE + c0];
        }
        float part = 0.f;
#pragma unroll
        for (int j = 0; j < J; j++) {
            float v = bits2f(ul[j]) + bits2f(ur[j]) + bits2f(uf[j]);
            v = v > 0.f ? v : 0.2f * v;
            part += v * attr[j];
        }
#pragma unroll
        for (int off = 32; off > 0; off >>= 1) part += __shfl_down(part, off, 64);
        if (lane == 0) logit_s[e * 4 + w] = part;
    }
    __syncthreads();
    if (tid < 64) logits[(size_t)s0 * 4 + tid] = logit_s[tid];
}

// ---------------- per-node softmax + gather-aggregate + bias + relu ----------
// logits/srcs are slot-ordered -> fully coalesced; only xl is a gather.
template<int HC, bool OUT_BF16>
__global__ __launch_bounds__(256) void node_agg_kernel(
    const unsigned short* __restrict__ xl, const float* __restrict__ logits,
    const int* __restrict__ srcs, const int* __restrict__ offsets,
    const float* __restrict__ bias, void* __restrict__ outv) {
    constexpr int V = HC / 256;   // 4 or 1
    int n = blockIdx.x, tid = threadIdx.x;
    int o0 = offsets[n];
    int deg = offsets[n + 1] - o0;
    __shared__ float s_m[4], s_s[4];
    int h = tid >> 6, lane = tid & 63;

    float m = -3.0e38f;
    for (int i = lane; i < deg; i += 64)
        m = fmaxf(m, logits[(size_t)(o0 + i) * 4 + h]);
#pragma unroll
    for (int off = 32; off > 0; off >>= 1) m = fmaxf(m, __shfl_down(m, off, 64));
    m = __shfl(m, 0, 64);
    float s = 0.f;
    for (int i = lane; i < deg; i += 64)
        s += expf(logits[(size_t)(o0 + i) * 4 + h] - m);
#pragma unroll
    for (int off = 32; off > 0; off >>= 1) s += __shfl_down(s, off, 64);
    if (lane == 0) { s_m[h] = m; s_s[h] = s; }
    __syncthreads();

    float mh = s_m[h];
    float inv = 1.f / (s_s[h] + 1e-16f);
    int c0 = tid * V;
    float acc[V];
#pragma unroll
    for (int v = 0; v < V; v++) acc[v] = bias[c0 + v];

    for (int i = 0; i < deg; i++) {
        int s_ = o0 + i;
        int src = srcs[s_];
        float alpha = expf(logits[(size_t)s_ * 4 + h] - mh) * inv;
        unsigned short us[V];
        if (V == 4) *(ushort4*)us = *(const ushort4*)&xl[(size_t)src * HC + c0];
        else us[0] = xl[(size_t)src * HC + c0];
#pragma unroll
        for (int v = 0; v < V; v++) acc[v] += alpha * bits2f(us[v]);
    }

    if (OUT_BF16) {
        unsigned short* o = (unsigned short*)outv;
        if (V == 4) {
            ushort4 u;
            u.x = f2bits(fmaxf(acc[0], 0.f));
            u.y = f2bits(fmaxf(acc[1], 0.f));
            u.z = f2bits(fmaxf(acc[2], 0.f));
            u.w = f2bits(fmaxf(acc[3], 0.f));
            *(ushort4*)&o[(size_t)n * HC + c0] = u;
        } else {
            o[(size_t)n * HC + c0] = f2bits(fmaxf(acc[0], 0.f));
        }
    } else {
        float* o = (float*)outv;
#pragma unroll
        for (int v = 0; v < V; v++) o[(size_t)n * HC + c0 + v] = fmaxf(acc[v], 0.f);
    }
}

// ---------------- master-node indices ----------------
__global__ void compute_last_kernel(const int* __restrict__ n_nodes, int* __restrict__ lastidx, int B) {
    if (blockIdx.x == 0 && threadIdx.x == 0) {
        int s = 0;
        for (int b = 0; b < B; b++) { s += n_nodes[b]; lastidx[b] = s - 1; }
    }
}

// ---------------- MLP head ----------------
__global__ __launch_bounds__(64) void mlp_head_kernel(
    const float* __restrict__ h2, const int* __restrict__ lastidx,
    const float* __restrict__ w1, const float* __restrict__ b1,
    const float* __restrict__ w2, const float* __restrict__ b2,
    float* __restrict__ out) {
    int b = blockIdx.x, tid = threadIdx.x;
    __shared__ float mast[256];
    int node = lastidx[b];
    for (int i = tid; i < 256; i += 64) mast[i] = h2[(size_t)node * 256 + i];
    __syncthreads();
    float z = 0.f;
    for (int k = 0; k < 256; k++) z += mast[k] * w1[k * 64 + tid];
    z += b1[tid];
    z = z > 0.f ? z : 0.f;
    float p = z * w2[tid];
#pragma unroll
    for (int off = 32; off > 0; off >>= 1) p += __shfl_down(p, off, 64);
    if (tid == 0) out[b] = p + b2[0];
}

extern "C" void kernel_launch(void* const* d_in, const int* in_sizes, int n_in,
                              void* d_out, int out_size, void* d_ws, size_t ws_size,
                              hipStream_t stream) {
    const float* x     = (const float*)d_in[0];
    const int*   ei    = (const int*)d_in[1];
    const float* eattr = (const float*)d_in[2];
    const int*   nnod  = (const int*)d_in[3];
    const float* Wl1 = (const float*)d_in[4];
    const float* bl1 = (const float*)d_in[5];
    const float* Wr1 = (const float*)d_in[6];
    const float* br1 = (const float*)d_in[7];
    const float* We1 = (const float*)d_in[8];
    const float* att1= (const float*)d_in[9];
    const float* b1  = (const float*)d_in[10];
    const float* Wl2 = (const float*)d_in[11];
    const float* bl2 = (const float*)d_in[12];
    const float* Wr2 = (const float*)d_in[13];
    const float* br2 = (const float*)d_in[14];
    const float* We2 = (const float*)d_in[15];
    const float* att2= (const float*)d_in[16];
    const float* b2  = (const float*)d_in[17];
    const float* fc1w= (const float*)d_in[18];
    const float* fc1b= (const float*)d_in[19];
    const float* fc2w= (const float*)d_in[20];
    const float* fc2b= (const float*)d_in[21];
    float* out = (float*)d_out;

    const int N = NN, E = EE, B = BB;

    // ---------- workspace layout (peak ~227 MB) ----------
    char* base = (char*)d_ws;
    const size_t NB1 = (size_t)N * 1024 * 2;
    unsigned short* xl1 = (unsigned short*)base;
    unsigned short* xl2 = (unsigned short*)base;
    unsigned short* xr2 = (unsigned short*)(base + (size_t)N * 256 * 2);
    float*          h2  = (float*)(base + (size_t)N * 256 * 4);
    unsigned short* xr1 = (unsigned short*)(base + NB1);
    unsigned short* h1  = (unsigned short*)(base + NB1);
    char* t = base + 2 * NB1;
    float* logits = (float*)t;        t += (size_t)E * 4 * sizeof(float);
    int* counts   = (int*)t;          t += (size_t)N * sizeof(int);
    int* offsets  = (int*)t;          t += (size_t)(N + 1) * sizeof(int);
    int* woff     = (int*)t;          t += (size_t)N * sizeof(int);
    int* perm     = (int*)t;          t += (size_t)E * sizeof(int);
    int* srcs     = (int*)t;          t += (size_t)E * sizeof(int);
    int* dsts     = (int*)t;          t += (size_t)E * sizeof(int);
    int* lastidx  = (int*)t;          t += (size_t)B * sizeof(int);
    unsigned short* xb   = (unsigned short*)t; t += (size_t)N * 128 * 2;
    unsigned short* wtl1 = (unsigned short*)t; t += (size_t)1024 * 128 * 2;
    unsigned short* wtr1 = (unsigned short*)t; t += (size_t)1024 * 128 * 2;
    unsigned short* wtl2 = (unsigned short*)t; t += (size_t)256 * 1024 * 2;
    unsigned short* wtr2 = (unsigned short*)t; t += (size_t)256 * 1024 * 2;
    unsigned short* weT1 = (unsigned short*)t; t += (size_t)1024 * 16 * 2;
    unsigned short* weT2 = (unsigned short*)t; t += (size_t)256 * 16 * 2;
    size_t required = (size_t)(t - base);
    if (ws_size < required) return;   // guard: absmax-fail instead of abort

    dim3 blk(256);

    // ---------- CSR build ----------
    zero_int_kernel<<<(N + 255) / 256, blk, 0, stream>>>(counts, N);
    hist_kernel<<<(E + 255) / 256, blk, 0, stream>>>(ei, counts, E);
    scan_kernel<<<1, 1024, 0, stream>>>(counts, offsets, woff, N);
    scatter_kernel<<<(E + 255) / 256, blk, 0, stream>>>(ei, woff, perm, srcs, dsts, E);

    // ---------- bf16 conversions ----------
    convert_bf16_kernel<<<(N * 128 + 255) / 256, blk, 0, stream>>>(x, xb, N * 128);
    convert_wt_kernel<<<(128 * 1024 + 255) / 256, blk, 0, stream>>>(Wl1, wtl1, 128, 1024);
    convert_wt_kernel<<<(128 * 1024 + 255) / 256, blk, 0, stream>>>(Wr1, wtr1, 128, 1024);
    convert_wt_kernel<<<(1024 * 256 + 255) / 256, blk, 0, stream>>>(Wl2, wtl2, 1024, 256);
    convert_wt_kernel<<<(1024 * 256 + 255) / 256, blk, 0, stream>>>(Wr2, wtr2, 1024, 256);
    convert_WeT_kernel<<<(1024 * 16 + 255) / 256, blk, 0, stream>>>(We1, weT1, 1024);
    convert_WeT_kernel<<<(256 * 16 + 255) / 256, blk, 0, stream>>>(We2, weT2, 256);

    // ---------- layer 1 ----------
    {
        dim3 g1(1024 / 128, N / 128);
        mfma_gemm_bt_kernel<<<g1, blk, 0, stream>>>(xb, wtl1, bl1, xl1, N, 128, 1024);
        mfma_gemm_bt_kernel<<<g1, blk, 0, stream>>>(xb, wtr1, br1, xr1, N, 128, 1024);
    }
    edge_score_v4_kernel<1024><<<E / 16, blk, 0, stream>>>(xl1, xr1, eattr, weT1, att1, perm, srcs, dsts, logits, E);
    node_agg_kernel<1024, true><<<N, blk, 0, stream>>>(xl1, logits, srcs, offsets, b1, h1);

    // ---------- layer 2 ----------
    {
        dim3 g2(256 / 128, N / 128);
        mfma_gemm_bt_kernel<<<g2, blk, 0, stream>>>(h1, wtl2, bl2, xl2, N, 1024, 256);
        mfma_gemm_bt_kernel<<<g2, blk, 0, stream>>>(h1, wtr2, br2, xr2, N, 1024, 256);
    }
    edge_score_v4_kernel<256><<<E / 16, blk, 0, stream>>>(xl2, xr2, eattr, weT2, att2, perm, srcs, dsts, logits, E);
    node_agg_kernel<256, false><<<N, blk, 0, stream>>>(xl2, logits, srcs, offsets, b2, h2);

    // ---------- head ----------
    compute_last_kernel<<<1, 64, 0, stream>>>(nnod, lastidx, B);
    mlp_head_kernel<<<B, 64, 0, stream>>>(h2, lastidx, fc1w, fc1b, fc2w, fc2b, out);
}

// Round 8
// 896.894 us; speedup vs baseline: 1.4820x; 1.1349x over previous
//
#include <hip/hip_runtime.h>
#include <hip/hip_bf16.h>
#include <cmath>

#define NN 49920
#define EE 200000
#define BB 128

typedef __attribute__((ext_vector_type(8))) short short8;
typedef __attribute__((ext_vector_type(4))) float floatx4;

__device__ __forceinline__ float bits2f(unsigned short u) {
    union { unsigned int i; float f; } c; c.i = ((unsigned int)u) << 16; return c.f;
}
__device__ __forceinline__ unsigned short f2bits(float f) {
    union { float f; unsigned int i; } c; c.f = f;
    unsigned int x = c.i;
    return (unsigned short)((x + 0x7fffu + ((x >> 16) & 1u)) >> 16);   // RNE, finite inputs
}

// async global->LDS, 16B per lane; LDS dest = wave-uniform base + lane*16
typedef const __attribute__((address_space(1))) void* gvp;
typedef __attribute__((address_space(3))) void* lvp;
__device__ __forceinline__ void gll16(const void* g, void* l) {
    __builtin_amdgcn_global_load_lds((gvp)g, (lvp)l, 16, 0, 0);
}

// ---------------- small utility kernels ----------------
__global__ void zero_int_kernel(int* __restrict__ p, int n) {
    int i = blockIdx.x * blockDim.x + threadIdx.x;
    if (i < n) p[i] = 0;
}

__global__ void convert_bf16_kernel(const float* __restrict__ src, unsigned short* __restrict__ dst, int n) {
    int i = blockIdx.x * blockDim.x + threadIdx.x;
    if (i < n) dst[i] = f2bits(src[i]);
}

// W [K][N] f32 -> WT [N][K] bf16
__global__ void convert_wt_kernel(const float* __restrict__ W, unsigned short* __restrict__ WT, int K, int N) {
    int i = blockIdx.x * blockDim.x + threadIdx.x;
    if (i < K * N) {
        int n = i / K, k = i - n * K;
        WT[i] = f2bits(W[(size_t)k * N + n]);
    }
}

// We [16][HC] f32 -> WeT [HC][16] bf16
__global__ void convert_WeT_kernel(const float* __restrict__ We, unsigned short* __restrict__ WeT, int HC) {
    int i = blockIdx.x * blockDim.x + threadIdx.x;
    if (i < HC * 16) {
        int col = i >> 4, k = i & 15;
        WeT[i] = f2bits(We[k * HC + col]);
    }
}

// ---------------- bf16 MFMA GEMM (B^T input, async staging) ----------------
// A [M,K] bf16, WT [N,K] bf16, bias[N] f32, C [M,N] bf16. 256 thr = 4 waves,
// 128x128 tile, BK=32. Staging via global_load_lds dwordx4 (m97 pattern):
// wave wid stages rows [wid*32, wid*32+32) of As and Bs; lane i lands at LDS
// byte base + i*16 == row (i>>2), kchunk (i&3)*16B  (row stride 64B).
__global__ __launch_bounds__(256) void mfma_gemm_bt_kernel(
    const unsigned short* __restrict__ A, const unsigned short* __restrict__ WT,
    const float* __restrict__ bias, unsigned short* __restrict__ C,
    int M, int K, int N) {
    __shared__ unsigned short As[128 * 32];
    __shared__ unsigned short Bs[128 * 32];
    int tid = threadIdx.x;
    int lane = tid & 63, wid = tid >> 6;
    int gm0 = blockIdx.y * 128, gn0 = blockIdx.x * 128;
    int wm = (wid & 1) * 64, wn = (wid >> 1) * 64;
    int l15 = lane & 15, quad = lane >> 4;
    int r0 = wid * 32;
    int gr = r0 + (lane >> 2);
    int kc = (lane & 3) * 8;

    floatx4 acc[4][4];
#pragma unroll
    for (int i = 0; i < 4; i++)
#pragma unroll
        for (int j = 0; j < 4; j++)
#pragma unroll
            for (int r = 0; r < 4; r++) acc[i][j][r] = 0.f;

    const unsigned short* Ap0 = &A[(size_t)(gm0 + gr) * K + kc];
    const unsigned short* Ap1 = Ap0 + (size_t)16 * K;
    const unsigned short* Bp0 = &WT[(size_t)(gn0 + gr) * K + kc];
    const unsigned short* Bp1 = Bp0 + (size_t)16 * K;
    unsigned short* as0 = &As[r0 * 32];
    unsigned short* as1 = &As[(r0 + 16) * 32];
    unsigned short* bs0 = &Bs[r0 * 32];
    unsigned short* bs1 = &Bs[(r0 + 16) * 32];

    for (int k0 = 0; k0 < K; k0 += 32) {
        __syncthreads();
        gll16(Ap0 + k0, as0);
        gll16(Ap1 + k0, as1);
        gll16(Bp0 + k0, bs0);
        gll16(Bp1 + k0, bs1);
        __syncthreads();
        short8 af[4], bfr[4];
#pragma unroll
        for (int i = 0; i < 4; i++)
            af[i] = *(const short8*)&As[(wm + 16 * i + l15) * 32 + quad * 8];
#pragma unroll
        for (int j = 0; j < 4; j++)
            bfr[j] = *(const short8*)&Bs[(wn + 16 * j + l15) * 32 + quad * 8];
#pragma unroll
        for (int i = 0; i < 4; i++)
#pragma unroll
            for (int j = 0; j < 4; j++)
                acc[i][j] = __builtin_amdgcn_mfma_f32_16x16x32_bf16(af[i], bfr[j], acc[i][j], 0, 0, 0);
    }

    int colb = gn0 + wn + l15;
#pragma unroll
    for (int i = 0; i < 4; i++) {
#pragma unroll
        for (int j = 0; j < 4; j++) {
            int col = colb + 16 * j;
            float bv = bias[col];
#pragma unroll
            for (int r = 0; r < 4; r++) {
                int rrow = gm0 + wm + 16 * i + quad * 4 + r;
                C[(size_t)rrow * N + col] = f2bits(acc[i][j][r] + bv);
            }
        }
    }
}

// ---------------- CSR build ----------------
__global__ void hist_kernel(const int* __restrict__ ei, int* __restrict__ counts, int E) {
    int e = blockIdx.x * blockDim.x + threadIdx.x;
    if (e < E) atomicAdd(&counts[ei[E + e]], 1);
}

__global__ __launch_bounds__(1024) void scan_kernel(
    const int* __restrict__ counts, int* __restrict__ offsets,
    int* __restrict__ woff, int N) {
    __shared__ int partial[1024];
    int tid = threadIdx.x;
    const int CH = (N + 1023) >> 10;
    int b0 = tid * CH;
    int s = 0;
    for (int i = 0; i < CH; i++) { int idx = b0 + i; if (idx < N) s += counts[idx]; }
    partial[tid] = s;
    __syncthreads();
    if (tid == 0) {
        int acc = 0;
        for (int i = 0; i < 1024; i++) { int t = partial[i]; partial[i] = acc; acc += t; }
        offsets[N] = acc;
    }
    __syncthreads();
    int run = partial[tid];
    for (int i = 0; i < CH; i++) {
        int idx = b0 + i;
        if (idx < N) { offsets[idx] = run; woff[idx] = run; run += counts[idx]; }
    }
}

__global__ void scatter_kernel(const int* __restrict__ ei, int* __restrict__ woff,
                               int* __restrict__ perm, int* __restrict__ srcs,
                               int* __restrict__ dsts, int E) {
    int e = blockIdx.x * blockDim.x + threadIdx.x;
    if (e < E) {
        int d = ei[E + e];
        int slot = atomicAdd(&woff[d], 1);
        perm[slot] = e;
        srcs[slot] = ei[e];
        dsts[slot] = d;
    }
}

// ---------------- edge scoring v5: slot-ordered, EB edges/block ----------------
template<int HC>
__global__ __launch_bounds__(256) void edge_score_v5_kernel(
    const unsigned short* __restrict__ xl, const unsigned short* __restrict__ xr,
    const float* __restrict__ eattr, const unsigned short* __restrict__ WeT,
    const float* __restrict__ att, const int* __restrict__ perm,
    const int* __restrict__ srcs, const int* __restrict__ dsts,
    float* __restrict__ logits, int E) {
    constexpr int EB = (HC == 1024) ? 8 : 16;   // edges per block (LDS-capped occupancy)
    constexpr int J = HC / 256;                  // 4 (L1) or 1 (L2)
    constexpr int LDE = HC + 8;
    __shared__ unsigned short ef_s[EB * LDE];
    __shared__ int src_s[EB], dst_s[EB], e_s[16];
    __shared__ float logit_s[EB * 4];

    int tid = threadIdx.x;
    int s0 = blockIdx.x * EB;
    int lane = tid & 63, w = tid >> 6;
    int l15 = lane & 15, quad = lane >> 4;

    if (tid < EB) { src_s[tid] = srcs[s0 + tid]; dst_s[tid] = dsts[s0 + tid]; }
    if (tid < 16) e_s[tid] = perm[s0 + (tid & (EB - 1))];
    __syncthreads();

    // A-frag: eattr rows for the EB slots (K zero-padded 16->32)
    union { short8 v; unsigned short u[8]; } a;
    if (quad < 2) {
        const float* ap = &eattr[(size_t)e_s[l15] * 16 + quad * 8];
        float4 a0 = *(const float4*)ap;
        float4 a1 = *(const float4*)(ap + 4);
        a.u[0] = f2bits(a0.x); a.u[1] = f2bits(a0.y); a.u[2] = f2bits(a0.z); a.u[3] = f2bits(a0.w);
        a.u[4] = f2bits(a1.x); a.u[5] = f2bits(a1.y); a.u[6] = f2bits(a1.z); a.u[7] = f2bits(a1.w);
    } else {
#pragma unroll
        for (int j = 0; j < 8; j++) a.u[j] = 0;
    }

    // Phase 1: ef = eattr @ We -> LDS (rows >= EB discarded)
    for (int t = w; t < HC / 16; t += 4) {
        int col = t * 16 + l15;
        union { short8 v; unsigned short u[8]; } b;
        if (quad < 2) *(uint4*)b.u = *(const uint4*)&WeT[(size_t)col * 16 + quad * 8];
        else {
#pragma unroll
            for (int j = 0; j < 8; j++) b.u[j] = 0;
        }
        floatx4 c = {0.f, 0.f, 0.f, 0.f};
        c = __builtin_amdgcn_mfma_f32_16x16x32_bf16(a.v, b.v, c, 0, 0, 0);
#pragma unroll
        for (int r = 0; r < 4; r++) {
            int row = quad * 4 + r;
            if (row < EB) ef_s[row * LDE + col] = f2bits(c[r]);
        }
    }
    __syncthreads();

    // Phase 2: thread owns channels c0=tid*J across all EB edges (coalesced)
    int c0 = tid * J;
    float attr[J];
#pragma unroll
    for (int j = 0; j < J; j++) attr[j] = att[c0 + j];

#pragma unroll 4
    for (int e = 0; e < EB; e++) {
        int src = src_s[e], dst = dst_s[e];
        unsigned short ul[J], ur[J], uf[J];
        if (J == 4) {
            *(ushort4*)ul = *(const ushort4*)&xl[(size_t)src * HC + c0];
            *(ushort4*)ur = *(const ushort4*)&xr[(size_t)dst * HC + c0];
            *(ushort4*)uf = *(const ushort4*)&ef_s[e * LDE + c0];
        } else {
            ul[0] = xl[(size_t)src * HC + c0];
            ur[0] = xr[(size_t)dst * HC + c0];
            uf[0] = ef_s[e * LDE + c0];
        }
        float part = 0.f;
#pragma unroll
        for (int j = 0; j < J; j++) {
            float v = bits2f(ul[j]) + bits2f(ur[j]) + bits2f(uf[j]);
            v = v > 0.f ? v : 0.2f * v;
            part += v * attr[j];
        }
#pragma unroll
        for (int off = 32; off > 0; off >>= 1) part += __shfl_down(part, off, 64);
        if (lane == 0) logit_s[e * 4 + w] = part;
    }
    __syncthreads();
    if (tid < EB * 4) logits[(size_t)s0 * 4 + tid] = logit_s[tid];
}

// ---------------- node aggregation: one WAVE per node ----------------
// 4 nodes/block. Lane owns J=HC/64 channels; head g = lane>>4; 16 lanes/head.
// Butterfly reduces within 16-lane groups; no LDS, no __syncthreads.
template<int HC, bool OUT_BF16>
__global__ __launch_bounds__(256) void node_agg_wave_kernel(
    const unsigned short* __restrict__ xl, const float* __restrict__ logits,
    const int* __restrict__ srcs, const int* __restrict__ offsets,
    const float* __restrict__ bias, void* __restrict__ outv) {
    constexpr int J = HC / 64;    // 16 (L1) or 4 (L2)
    int tid = threadIdx.x;
    int wid = tid >> 6, lane = tid & 63;
    int n = blockIdx.x * 4 + wid;
    int o0 = offsets[n];
    int deg = offsets[n + 1] - o0;
    int g = lane >> 4, p = lane & 15;

    float m = -3.0e38f;
    for (int i = p; i < deg; i += 16)
        m = fmaxf(m, logits[(size_t)(o0 + i) * 4 + g]);
    m = fmaxf(m, __shfl_xor(m, 1, 64));
    m = fmaxf(m, __shfl_xor(m, 2, 64));
    m = fmaxf(m, __shfl_xor(m, 4, 64));
    m = fmaxf(m, __shfl_xor(m, 8, 64));
    float s = 0.f;
    for (int i = p; i < deg; i += 16)
        s += expf(logits[(size_t)(o0 + i) * 4 + g] - m);
    s += __shfl_xor(s, 1, 64);
    s += __shfl_xor(s, 2, 64);
    s += __shfl_xor(s, 4, 64);
    s += __shfl_xor(s, 8, 64);
    float inv = 1.f / (s + 1e-16f);

    int c0 = lane * J;
    float acc[J];
#pragma unroll
    for (int v = 0; v < J; v++) acc[v] = bias[c0 + v];

    for (int i = 0; i < deg; i++) {
        int sl = o0 + i;
        float alpha = expf(logits[(size_t)sl * 4 + g] - m) * inv;
        int src = srcs[sl];
        const unsigned short* row = &xl[(size_t)src * HC + c0];
        if constexpr (J == 16) {
            union { short8 v; unsigned short u[8]; } a0, a1;
            a0.v = *(const short8*)row;
            a1.v = *(const short8*)(row + 8);
#pragma unroll
            for (int v = 0; v < 8; v++) acc[v] += alpha * bits2f(a0.u[v]);
#pragma unroll
            for (int v = 0; v < 8; v++) acc[8 + v] += alpha * bits2f(a1.u[v]);
        } else {
            unsigned short us[4];
            *(ushort4*)us = *(const ushort4*)row;
#pragma unroll
            for (int v = 0; v < 4; v++) acc[v] += alpha * bits2f(us[v]);
        }
    }

    if constexpr (OUT_BF16) {
        unsigned short* o = (unsigned short*)outv;
        union { short8 v; unsigned short u[8]; } w0, w1;
#pragma unroll
        for (int v = 0; v < 8; v++) w0.u[v] = f2bits(fmaxf(acc[v], 0.f));
#pragma unroll
        for (int v = 0; v < 8; v++) w1.u[v] = f2bits(fmaxf(acc[8 + v], 0.f));
        *(short8*)&o[(size_t)n * HC + c0] = w0.v;
        *(short8*)&o[(size_t)n * HC + c0 + 8] = w1.v;
    } else {
        float* o = (float*)outv;
#pragma unroll
        for (int v = 0; v < J; v++) o[(size_t)n * HC + c0 + v] = fmaxf(acc[v], 0.f);
    }
}

// ---------------- master-node indices ----------------
__global__ void compute_last_kernel(const int* __restrict__ n_nodes, int* __restrict__ lastidx, int B) {
    if (blockIdx.x == 0 && threadIdx.x == 0) {
        int s = 0;
        for (int b = 0; b < B; b++) { s += n_nodes[b]; lastidx[b] = s - 1; }
    }
}

// ---------------- MLP head ----------------
__global__ __launch_bounds__(64) void mlp_head_kernel(
    const float* __restrict__ h2, const int* __restrict__ lastidx,
    const float* __restrict__ w1, const float* __restrict__ b1,
    const float* __restrict__ w2, const float* __restrict__ b2,
    float* __restrict__ out) {
    int b = blockIdx.x, tid = threadIdx.x;
    __shared__ float mast[256];
    int node = lastidx[b];
    for (int i = tid; i < 256; i += 64) mast[i] = h2[(size_t)node * 256 + i];
    __syncthreads();
    float z = 0.f;
    for (int k = 0; k < 256; k++) z += mast[k] * w1[k * 64 + tid];
    z += b1[tid];
    z = z > 0.f ? z : 0.f;
    float p = z * w2[tid];
#pragma unroll
    for (int off = 32; off > 0; off >>= 1) p += __shfl_down(p, off, 64);
    if (tid == 0) out[b] = p + b2[0];
}

extern "C" void kernel_launch(void* const* d_in, const int* in_sizes, int n_in,
                              void* d_out, int out_size, void* d_ws, size_t ws_size,
                              hipStream_t stream) {
    const float* x     = (const float*)d_in[0];
    const int*   ei    = (const int*)d_in[1];
    const float* eattr = (const float*)d_in[2];
    const int*   nnod  = (const int*)d_in[3];
    const float* Wl1 = (const float*)d_in[4];
    const float* bl1 = (const float*)d_in[5];
    const float* Wr1 = (const float*)d_in[6];
    const float* br1 = (const float*)d_in[7];
    const float* We1 = (const float*)d_in[8];
    const float* att1= (const float*)d_in[9];
    const float* b1  = (const float*)d_in[10];
    const float* Wl2 = (const float*)d_in[11];
    const float* bl2 = (const float*)d_in[12];
    const float* Wr2 = (const float*)d_in[13];
    const float* br2 = (const float*)d_in[14];
    const float* We2 = (const float*)d_in[15];
    const float* att2= (const float*)d_in[16];
    const float* b2  = (const float*)d_in[17];
    const float* fc1w= (const float*)d_in[18];
    const float* fc1b= (const float*)d_in[19];
    const float* fc2w= (const float*)d_in[20];
    const float* fc2b= (const float*)d_in[21];
    float* out = (float*)d_out;

    const int N = NN, E = EE, B = BB;

    // ---------- workspace layout (peak ~227 MB) ----------
    char* base = (char*)d_ws;
    const size_t NB1 = (size_t)N * 1024 * 2;
    unsigned short* xl1 = (unsigned short*)base;
    unsigned short* xl2 = (unsigned short*)base;
    unsigned short* xr2 = (unsigned short*)(base + (size_t)N * 256 * 2);
    float*          h2  = (float*)(base + (size_t)N * 256 * 4);
    unsigned short* xr1 = (unsigned short*)(base + NB1);
    unsigned short* h1  = (unsigned short*)(base + NB1);
    char* t = base + 2 * NB1;
    float* logits = (float*)t;        t += (size_t)E * 4 * sizeof(float);
    int* counts   = (int*)t;          t += (size_t)N * sizeof(int);
    int* offsets  = (int*)t;          t += (size_t)(N + 1) * sizeof(int);
    int* woff     = (int*)t;          t += (size_t)N * sizeof(int);
    int* perm     = (int*)t;          t += (size_t)E * sizeof(int);
    int* srcs     = (int*)t;          t += (size_t)E * sizeof(int);
    int* dsts     = (int*)t;          t += (size_t)E * sizeof(int);
    int* lastidx  = (int*)t;          t += (size_t)B * sizeof(int);
    t = (char*)(((uintptr_t)t + 63) & ~(uintptr_t)63);   // 64B-align bf16 buffers
    unsigned short* xb   = (unsigned short*)t; t += (size_t)N * 128 * 2;
    unsigned short* wtl1 = (unsigned short*)t; t += (size_t)1024 * 128 * 2;
    unsigned short* wtr1 = (unsigned short*)t; t += (size_t)1024 * 128 * 2;
    unsigned short* wtl2 = (unsigned short*)t; t += (size_t)256 * 1024 * 2;
    unsigned short* wtr2 = (unsigned short*)t; t += (size_t)256 * 1024 * 2;
    unsigned short* weT1 = (unsigned short*)t; t += (size_t)1024 * 16 * 2;
    unsigned short* weT2 = (unsigned short*)t; t += (size_t)256 * 16 * 2;
    size_t required = (size_t)(t - base);
    if (ws_size < required) return;   // guard: absmax-fail instead of abort

    dim3 blk(256);

    // ---------- CSR build ----------
    zero_int_kernel<<<(N + 255) / 256, blk, 0, stream>>>(counts, N);
    hist_kernel<<<(E + 255) / 256, blk, 0, stream>>>(ei, counts, E);
    scan_kernel<<<1, 1024, 0, stream>>>(counts, offsets, woff, N);
    scatter_kernel<<<(E + 255) / 256, blk, 0, stream>>>(ei, woff, perm, srcs, dsts, E);

    // ---------- bf16 conversions ----------
    convert_bf16_kernel<<<(N * 128 + 255) / 256, blk, 0, stream>>>(x, xb, N * 128);
    convert_wt_kernel<<<(128 * 1024 + 255) / 256, blk, 0, stream>>>(Wl1, wtl1, 128, 1024);
    convert_wt_kernel<<<(128 * 1024 + 255) / 256, blk, 0, stream>>>(Wr1, wtr1, 128, 1024);
    convert_wt_kernel<<<(1024 * 256 + 255) / 256, blk, 0, stream>>>(Wl2, wtl2, 1024, 256);
    convert_wt_kernel<<<(1024 * 256 + 255) / 256, blk, 0, stream>>>(Wr2, wtr2, 1024, 256);
    convert_WeT_kernel<<<(1024 * 16 + 255) / 256, blk, 0, stream>>>(We1, weT1, 1024);
    convert_WeT_kernel<<<(256 * 16 + 255) / 256, blk, 0, stream>>>(We2, weT2, 256);

    // ---------- layer 1 ----------
    {
        dim3 g1(1024 / 128, N / 128);
        mfma_gemm_bt_kernel<<<g1, blk, 0, stream>>>(xb, wtl1, bl1, xl1, N, 128, 1024);
        mfma_gemm_bt_kernel<<<g1, blk, 0, stream>>>(xb, wtr1, br1, xr1, N, 128, 1024);
    }
    edge_score_v5_kernel<1024><<<E / 8, blk, 0, stream>>>(xl1, xr1, eattr, weT1, att1, perm, srcs, dsts, logits, E);
    node_agg_wave_kernel<1024, true><<<N / 4, blk, 0, stream>>>(xl1, logits, srcs, offsets, b1, h1);

    // ---------- layer 2 ----------
    {
        dim3 g2(256 / 128, N / 128);
        mfma_gemm_bt_kernel<<<g2, blk, 0, stream>>>(h1, wtl2, bl2, xl2, N, 1024, 256);
        mfma_gemm_bt_kernel<<<g2, blk, 0, stream>>>(h1, wtr2, br2, xr2, N, 1024, 256);
    }
    edge_score_v5_kernel<256><<<E / 16, blk, 0, stream>>>(xl2, xr2, eattr, weT2, att2, perm, srcs, dsts, logits, E);
    node_agg_wave_kernel<256, false><<<N / 4, blk, 0, stream>>>(xl2, logits, srcs, offsets, b2, h2);

    // ---------- head ----------
    compute_last_kernel<<<1, 64, 0, stream>>>(nnod, lastidx, B);
    mlp_head_kernel<<<B, 64, 0, stream>>>(h2, lastidx, fc1w, fc1b, fc2w, fc2b, out);
}